// Round 7
// baseline (334.461 us; speedup 1.0000x reference)
//
#include <hip/hip_runtime.h>
#include <cstddef>
#include <cstdint>

#define LEN_T 11253
#define TOK   22506     // BS * LEN
#define NHEADS 8
#define DMODEL 256

#define SBAR() __builtin_amdgcn_sched_barrier(0)

typedef __attribute__((ext_vector_type(8))) short short8;   // bf16x8 (4 VGPR)
typedef __attribute__((ext_vector_type(4))) float f32x4;

__device__ __forceinline__ unsigned short f2bf(float f) {
  union { float f; unsigned u; } v; v.f = f;
  unsigned r = v.u + 0x7fffu + ((v.u >> 16) & 1u);   // RNE
  return (unsigned short)(r >> 16);
}
__device__ __forceinline__ float bfhi2f(unsigned u) {
  union { unsigned u; float f; } v; v.u = u & 0xffff0000u; return v.f;
}
__device__ __forceinline__ float bflo2f(unsigned u) {
  union { unsigned u; float f; } v; v.u = u << 16; return v.f;
}
__device__ __forceinline__ float bf2f(unsigned short s) {
  union { unsigned u; float f; } v; v.u = (unsigned)s << 16; return v.f;
}
__device__ __forceinline__ void gld_lds16(const void* g, void* l) {
  __builtin_amdgcn_global_load_lds(
      (const __attribute__((address_space(1))) void*)g,
      (__attribute__((address_space(3))) void*)l, 16, 0, 0);
}

// branchless stable top-4 insert (desc, strict > : earlier index wins ties)
__device__ __forceinline__ void ins4(float v, int ji,
    float& t0, float& t1, float& t2, float& t3,
    int& i0, int& i1, int& i2, int& i3)
{
  bool a0 = v > t0, a1 = v > t1, a2 = v > t2, a3 = v > t3;
  t3 = a3 ? (a2 ? t2 : v) : t3;  i3 = a3 ? (a2 ? i2 : ji) : i3;
  t2 = a2 ? (a1 ? t1 : v) : t2;  i2 = a2 ? (a1 ? i1 : ji) : i2;
  t1 = a1 ? (a0 ? t0 : v) : t1;  i1 = a1 ? (a0 ? i0 : ji) : i1;
  t0 = a0 ? v : t0;              i0 = a0 ? ji : i0;
}

// ==== pre-kernel: top-k + weight casts + src f32->bf16 cast ====
// blocks [0,704): topk, one THREAD per (b,q,h)
// blocks [704,1344): weight cast+transpose, 4 elems/thread
// blocks [1344,4160): src -> bf16 cast (src_bf lives in h1's region)
__global__ __launch_bounds__(256) void pre_kernel(
    const float* __restrict__ src, unsigned short* __restrict__ src_bf,
    const float* __restrict__ m0, const float* __restrict__ m1,
    const float* __restrict__ m2, const float* __restrict__ m3,
    const float* __restrict__ pm_w, const float* __restrict__ pm_b,
    const float* __restrict__ Wv, const float* __restrict__ Wo,
    const float* __restrict__ W1, const float* __restrict__ W2,
    unsigned short* __restrict__ Wv_t, unsigned short* __restrict__ Wo_t,
    unsigned short* __restrict__ W1_t, unsigned short* __restrict__ W2_t,
    unsigned* __restrict__ offp, float* __restrict__ attw)
{
  int blk = blockIdx.x;
  if (blk >= 1344) {   // ---- src cast: 8 elems/thread
    int i = (blk - 1344) * 2048 + threadIdx.x * 8;
    if (i < TOK * DMODEL) {
      float4 a = *(const float4*)(src + i);
      float4 b = *(const float4*)(src + i + 4);
      uint4 o;
      o.x = (unsigned)f2bf(a.x) | ((unsigned)f2bf(a.y) << 16);
      o.y = (unsigned)f2bf(a.z) | ((unsigned)f2bf(a.w) << 16);
      o.z = (unsigned)f2bf(b.x) | ((unsigned)f2bf(b.y) << 16);
      o.w = (unsigned)f2bf(b.z) | ((unsigned)f2bf(b.w) << 16);
      *(uint4*)(src_bf + i) = o;
    }
    return;
  }
  if (blk >= 704) {   // ---- weight cast+transpose: Bt[n][k] = bf16(W[k][n])
    int cb = blk - 704;
    const float* W; unsigned short* Bt; int lk, ln, base;
    if (cb < 64)       { W = Wv; Bt = Wv_t; lk = 8;  ln = 8;  base = cb; }
    else if (cb < 128) { W = Wo; Bt = Wo_t; lk = 8;  ln = 8;  base = cb - 64; }
    else if (cb < 384) { W = W1; Bt = W1_t; lk = 8;  ln = 10; base = cb - 128; }
    else               { W = W2; Bt = W2_t; lk = 10; ln = 8;  base = cb - 384; }
    int i4 = (base * 256 + threadIdx.x) * 4;
    int n  = i4 >> lk;
    int k  = i4 & ((1 << lk) - 1);
    ushort4 o;
    o.x = f2bf(W[((size_t)(k + 0) << ln) + n]);
    o.y = f2bf(W[((size_t)(k + 1) << ln) + n]);
    o.z = f2bf(W[((size_t)(k + 2) << ln) + n]);
    o.w = f2bf(W[((size_t)(k + 3) << ln) + n]);
    *(ushort4*)(Bt + i4) = o;
    return;
  }
  // ---- top-k: one thread per (b, q, h) ----
  int t = blk * 256 + threadIdx.x;
  if (t >= TOK * NHEADS) return;
  int h  = t & 7;
  int bq = t >> 3;
  int b  = bq / LEN_T;
  int q  = bq - b * LEN_T;
  int l, H_, W_;
  const float* mk;
  if (q < 8464)       { l = 0; H_ = 92; W_ = 92; mk = m0; }
  else if (q < 10580) { l = 1; H_ = 46; W_ = 46; mk = m1; }
  else if (q < 11109) { l = 2; H_ = 23; W_ = 23; mk = m2; }
  else                { l = 3; H_ = 12; W_ = 12; mk = m3; }
  int st = (l == 0) ? 0 : (l == 1) ? 8464 : (l == 2) ? 10580 : 11109;
  int pos = q - st;
  int rr = pos / W_;
  int cc = pos - rr * W_;
  float w  = pm_w[l * NHEADS + h];
  float bb = pm_b[l * NHEADS + h];
  const float* mp = mk + (size_t)b * H_ * W_;

  float t0=-1e30f,t1=-1e30f,t2=-1e30f,t3=-1e30f;
  int   i0=0,i1=0,i2=0,i3=0;
  for (int i = 0; i < 7; ++i) {
    int yy = rr + i - 3;
    #pragma unroll
    for (int j = 0; j < 7; ++j) {
      int xx = cc + j - 3;
      float v = 0.f;                       // zero padding outside the map
      if (yy >= 0 && yy < H_ && xx >= 0 && xx < W_)
        v = mp[(size_t)yy * W_ + xx] * w + bb;
      ins4(v, j | (i << 4), t0, t1, t2, t3, i0, i1, i2, i3);
    }
  }
  float e1 = __expf(t1 - t0);
  float e2 = __expf(t2 - t0);
  float e3 = __expf(t3 - t0);
  float inv = 1.f / (4.f * (1.f + e1 + e2 + e3));
  float4 wout; wout.x = inv; wout.y = e1 * inv; wout.z = e2 * inv; wout.w = e3 * inv;
  *(float4*)(attw + (size_t)t * 4) = wout;
  offp[t] = (unsigned)i0 | ((unsigned)i1 << 8)
          | ((unsigned)i2 << 16) | ((unsigned)i3 << 24);
}

// ---------------- deformable bilinear sampling (bf16 V, v3) ----------------
// one wave per token; XCD-contiguous token swizzle for L2 locality.
// grid MUST be 5627 blocks (= 8*703 + 3).
__global__ __launch_bounds__(256) void sample_kernel(
    const unsigned short* __restrict__ Vb, const float* __restrict__ refpts,
    const unsigned* __restrict__ offp, const float* __restrict__ attw,
    unsigned short* __restrict__ outp)
{
  __shared__ int4  sidx[4][128];
  __shared__ float4 swgt[4][128];
  const int wv   = threadIdx.x >> 6;
  const int lane = threadIdx.x & 63;
  const int bx = blockIdx.x & 7, by = blockIdx.x >> 3;
  const int nb = bx * 703 + min(bx, 3) + by;
  const int blk = nb * 4 + wv;             // b*LEN + q
  const bool ok = blk < TOK;

  if (ok) {
    const int b = (blk >= LEN_T) ? 1 : 0;
    const float* rp = refpts + (size_t)blk * 8;
    #pragma unroll
    for (int e = 0; e < 2; ++e) {
      int t = lane * 2 + e;                // t = lp*8 + h
      int h = t & 7, lp = t >> 3;
      int l = lp >> 2, p = lp & 3;
      unsigned pb = (offp[(size_t)blk * 8 + h] >> (8 * p)) & 0xffu;
      float ox = (float)(int)(pb & 15u) - 3.f;
      float oy = (float)(int)(pb >> 4)  - 3.f;
      float aw = attw[((size_t)blk * 8 + h) * 4 + p];
      int H_ = (l == 0) ? 92 : (l == 1) ? 46 : (l == 2) ? 23 : 12;
      int st = (l == 0) ? 0  : (l == 1) ? 8464 : (l == 2) ? 10580 : 11109;
      float xx = rp[2 * l]     * (float)H_ - 0.5f + ox;
      float yy = rp[2 * l + 1] * (float)H_ - 0.5f + oy;
      float x0f = floorf(xx), y0f = floorf(yy);
      float tx = xx - x0f, ty = yy - y0f;
      int x0 = (int)x0f, y0 = (int)y0f;
      int base = b * LEN_T + st;
      float wc[4] = {(1.f - tx) * (1.f - ty), tx * (1.f - ty),
                     (1.f - tx) * ty,         tx * ty};
      int4 idx; float4 wg;
      int xs[4] = {x0, x0 + 1, x0, x0 + 1};
      int ys[4] = {y0, y0, y0 + 1, y0 + 1};
      int   id[4]; float wgt[4];
      #pragma unroll
      for (int c = 0; c < 4; ++c) {
        int xi = xs[c], yi = ys[c];
        bool v_ = (xi >= 0) & (xi < H_) & (yi >= 0) & (yi < H_);
        id[c]  = base + min(max(yi, 0), H_ - 1) * H_ + min(max(xi, 0), H_ - 1);
        wgt[c] = v_ ? aw * wc[c] : 0.f;
      }
      idx.x = id[0]; idx.y = id[1]; idx.z = id[2]; idx.w = id[3];
      wg.x = wgt[0]; wg.y = wgt[1]; wg.z = wgt[2]; wg.w = wgt[3];
      sidx[wv][t] = idx;
      swgt[wv][t] = wg;
    }
  }
  __syncthreads();

  if (ok) {
    const int h = lane >> 3, dg = lane & 7;
    const unsigned short* vb = Vb + h * 32 + dg * 4;   // 4 bf16 = 8B per lane
    f32x4 acc = {0.f, 0.f, 0.f, 0.f};

    // double-buffered pipeline state; ALL indices compile-time after unroll
    uint2  u[2][8];
    float4 wg[2][2];

    // issue batch 0 (lp = 0,1)
    #pragma unroll
    for (int j = 0; j < 2; ++j) {
      int4 idx  = sidx[wv][j * 8 + h];
      wg[0][j]  = swgt[wv][j * 8 + h];
      u[0][j*4+0] = *(const uint2*)(vb + (size_t)idx.x * DMODEL);
      u[0][j*4+1] = *(const uint2*)(vb + (size_t)idx.y * DMODEL);
      u[0][j*4+2] = *(const uint2*)(vb + (size_t)idx.z * DMODEL);
      u[0][j*4+3] = *(const uint2*)(vb + (size_t)idx.w * DMODEL);
    }
    SBAR();
    #pragma unroll
    for (int bt = 0; bt < 8; ++bt) {
      const int cur = bt & 1, nxt = cur ^ 1;
      if (bt < 7) {      // issue batch bt+1 while batch bt's data arrives
        #pragma unroll
        for (int j = 0; j < 2; ++j) {
          int lp = (bt + 1) * 2 + j;
          int4 idx   = sidx[wv][lp * 8 + h];
          wg[nxt][j] = swgt[wv][lp * 8 + h];
          u[nxt][j*4+0] = *(const uint2*)(vb + (size_t)idx.x * DMODEL);
          u[nxt][j*4+1] = *(const uint2*)(vb + (size_t)idx.y * DMODEL);
          u[nxt][j*4+2] = *(const uint2*)(vb + (size_t)idx.z * DMODEL);
          u[nxt][j*4+3] = *(const uint2*)(vb + (size_t)idx.w * DMODEL);
        }
      }
      SBAR();            // pin: prefetch issued above, consume below
      #pragma unroll
      for (int j = 0; j < 2; ++j) {
        const float4 w4 = wg[cur][j];
        const uint2 u0 = u[cur][j*4+0], u1 = u[cur][j*4+1];
        const uint2 u2 = u[cur][j*4+2], u3 = u[cur][j*4+3];
        acc.x += w4.x * bflo2f(u0.x) + w4.y * bflo2f(u1.x) + w4.z * bflo2f(u2.x) + w4.w * bflo2f(u3.x);
        acc.y += w4.x * bfhi2f(u0.x) + w4.y * bfhi2f(u1.x) + w4.z * bfhi2f(u2.x) + w4.w * bfhi2f(u3.x);
        acc.z += w4.x * bflo2f(u0.y) + w4.y * bflo2f(u1.y) + w4.z * bflo2f(u2.y) + w4.w * bflo2f(u3.y);
        acc.w += w4.x * bfhi2f(u0.y) + w4.y * bfhi2f(u1.y) + w4.z * bfhi2f(u2.y) + w4.w * bfhi2f(u3.y);
      }
    }
    uint2 o;
    o.x = (unsigned)f2bf(acc.x) | ((unsigned)f2bf(acc.y) << 16);
    o.y = (unsigned)f2bf(acc.z) | ((unsigned)f2bf(acc.w) << 16);
    *(uint2*)(outp + (size_t)blk * DMODEL + h * 32 + dg * 4) = o;
  }
}

// ========== v6: coalesced-A whole-tile-staged streaming MFMA GEMM ==========
// C[M,N] = A[M,K] @ Bt[N,K]^T. Block = 32(M) x 256(N), 4 waves (wave: 32x64).
// The WHOLE 32-row x K A-tile is staged ONCE into LDS with sequentially
// coalesced gld_lds: each wave-instruction covers one contiguous 1KB stretch
// (lane -> base + lane*16B), only permuting 16B slots WITHIN each 64B group
// (same cache lines -> full coalescing) as bank swizzle. K-loop then has NO
// barriers and NO global-A traffic: 2 ds_read_b128 + 4 B loads (B is 128-512KB,
// L2-resident) + 8 MFMA per step, B double-buffered in registers.
// Rationale: rounds 0-6 all hit ~1 TB/s — scattered 16-64B granule staging at
// 512B-2KB strides is the ceiling. This kernel streams A at full line rate.
// Swizzle algebra: LDS[r][s] = A[r][(s&~3)|((s&3)^(r&3))]; fragment read at
// slot (quad^(r&3)) yields global k-slot quad. 4 lanes/slot = 4-way (1.58x).
// EPI 0: Cb=bf16(acc+bias)  EPI 1: LN(+res_f32)->Cb  EPI 2: relu->Cb
// EPI 3: LN(+resb_bf16)->C f32
template<int EPI, int LOG2K>
__global__ __launch_bounds__(256, 2) void gemm_v6(
    const short* __restrict__ Ab, const short* __restrict__ Bt,
    const float* __restrict__ bias, const float* __restrict__ res,
    const unsigned short* __restrict__ resb,
    const float* __restrict__ lng, const float* __restrict__ lnb,
    float* __restrict__ C, unsigned short* __restrict__ Cb,
    int M, int N)
{
  constexpr int K  = 1 << LOG2K;
  constexpr int NK = K / 32;           // 32-wide K steps
  constexpr int NI = K / 64;           // staging instrs per wave (1KB each)
  __shared__ short As[32 * K] __attribute__((aligned(16)));
  __shared__ float2 lnred[32][4];
  const int tid = threadIdx.x, w = tid >> 6, lane = tid & 63;
  const int row0 = blockIdx.x * 32;
  const int wn0  = blockIdx.y * 256 + w * 64;
  const int colq = lane & 15, quad = lane >> 4;

  f32x4 acc[2][4];
  #pragma unroll
  for (int i = 0; i < 2; ++i)
    #pragma unroll
    for (int j = 0; j < 4; ++j) acc[i][j] = (f32x4){0.f, 0.f, 0.f, 0.f};

  // ---- stage whole A tile, fully coalesced (1KB contiguous per instr) ----
  {
    const size_t gb = (size_t)row0 << LOG2K;     // tile base (shorts)
    #pragma unroll
    for (int i = 0; i < NI; ++i) {
      int o   = w * (8 << LOG2K) + i * 512 + lane * 8;   // linear short offset
      int r   = o >> LOG2K;                              // row of this 16B
      int src = (o & ~31) | (((((o >> 3) & 3) ^ (r & 3)) & 3) << 3);
      gld_lds16(Ab + gb + src, As + o);
    }
  }

  // B: 64 cols/wave read straight from global (L2-resident), double-buffered
  short8 bqA[4], bqB[4];
  auto loadB = [&](int kb, short8* dst) {
    #pragma unroll
    for (int nt = 0; nt < 4; ++nt)
      dst[nt] = *(const short8*)(Bt + ((size_t)(wn0 + nt * 16 + colq) << LOG2K)
                                    + kb * 32 + quad * 8);
  };
  loadB(0, bqA);
  __syncthreads();           // drains gld_lds (compiler emits vmcnt(0) here)

  #pragma unroll
  for (int kb = 0; kb < NK; ++kb) {
    short8* cur = (kb & 1) ? bqB : bqA;
    short8* nxt = (kb & 1) ? bqA : bqB;
    if (kb + 1 < NK) loadB(kb + 1, nxt);
    short8 af[2];
    #pragma unroll
    for (int mt = 0; mt < 2; ++mt) {
      int r = mt * 16 + colq;
      af[mt] = *(const short8*)(As + ((size_t)r << LOG2K) + kb * 32
                                + ((quad ^ (r & 3)) << 3));
    }
    #pragma unroll
    for (int mt = 0; mt < 2; ++mt)
      #pragma unroll
      for (int nt = 0; nt < 4; ++nt)
        acc[mt][nt] = __builtin_amdgcn_mfma_f32_16x16x32_bf16(
            af[mt], cur[nt], acc[mt][nt], 0, 0, 0);
  }

  // ---- epilogue: C/D layout col = lane&15, row = quad*4 + reg ----
  float bia[4];
  #pragma unroll
  for (int nt = 0; nt < 4; ++nt) bia[nt] = bias[wn0 + nt * 16 + colq];

  if constexpr (EPI == 1 || EPI == 3) {
    #pragma unroll
    for (int mt = 0; mt < 2; ++mt) {
      #pragma unroll
      for (int r = 0; r < 4; ++r) {
        int lrow = mt * 16 + quad * 4 + r;
        int rowc = min(row0 + lrow, M - 1);
        float s = 0.f, sq = 0.f;
        #pragma unroll
        for (int nt = 0; nt < 4; ++nt) {
          float rv;
          if constexpr (EPI == 1)
            rv = res[(size_t)rowc * 256 + wn0 + nt * 16 + colq];
          else
            rv = bf2f(resb[(size_t)rowc * 256 + wn0 + nt * 16 + colq]);
          float f = acc[mt][nt][r] + bia[nt] + rv;
          acc[mt][nt][r] = f;
          s += f; sq += f * f;
        }
        #pragma unroll
        for (int off = 1; off < 16; off <<= 1) {
          s  += __shfl_xor(s,  off, 64);
          sq += __shfl_xor(sq, off, 64);
        }
        if (colq == 0) lnred[lrow][w] = (float2){s, sq};
      }
    }
    __syncthreads();
    #pragma unroll
    for (int mt = 0; mt < 2; ++mt) {
      #pragma unroll
      for (int r = 0; r < 4; ++r) {
        int lrow = mt * 16 + quad * 4 + r;
        int row  = row0 + lrow;
        if (row >= M) continue;
        float2 p0 = lnred[lrow][0], p1 = lnred[lrow][1];
        float2 p2 = lnred[lrow][2], p3 = lnred[lrow][3];
        float mu  = (p0.x + p1.x + p2.x + p3.x) * (1.f / 256.f);
        float var = (p0.y + p1.y + p2.y + p3.y) * (1.f / 256.f) - mu * mu;
        float rs  = rsqrtf(var + 1e-5f);          // biased var (jnp.var)
        #pragma unroll
        for (int nt = 0; nt < 4; ++nt) {
          int col = wn0 + nt * 16 + colq;
          float o = (acc[mt][nt][r] - mu) * rs * lng[col] + lnb[col];
          if constexpr (EPI == 1)
            Cb[(size_t)row * 256 + col] = f2bf(o);
          else
            C[(size_t)row * 256 + col] = o;
        }
      }
    }
  } else {
    #pragma unroll
    for (int mt = 0; mt < 2; ++mt) {
      #pragma unroll
      for (int r = 0; r < 4; ++r) {
        int row = row0 + mt * 16 + quad * 4 + r;
        if (row < M) {
          #pragma unroll
          for (int nt = 0; nt < 4; ++nt) {
            float f = acc[mt][nt][r] + bia[nt];
            if constexpr (EPI == 2) f = fmaxf(f, 0.f);
            Cb[(size_t)row * N + wn0 + nt * 16 + colq] = f2bf(f);
          }
        }
      }
    }
  }
}

extern "C" void kernel_launch(void* const* d_in, const int* in_sizes, int n_in,
                              void* d_out, int out_size, void* d_ws, size_t ws_size,
                              hipStream_t stream)
{
  const float* src    = (const float*)d_in[0];
  const float* refpts = (const float*)d_in[2];
  const float* m0   = (const float*)d_in[4];
  const float* m1   = (const float*)d_in[5];
  const float* m2   = (const float*)d_in[6];
  const float* m3   = (const float*)d_in[7];
  const float* pm_w = (const float*)d_in[10];
  const float* pm_b = (const float*)d_in[11];
  const float* Wv   = (const float*)d_in[12];
  const float* bv   = (const float*)d_in[13];
  const float* Wo   = (const float*)d_in[14];
  const float* bo   = (const float*)d_in[15];
  const float* ln1g = (const float*)d_in[16];
  const float* ln1b = (const float*)d_in[17];
  const float* W1   = (const float*)d_in[18];
  const float* b1   = (const float*)d_in[19];
  const float* W2   = (const float*)d_in[20];
  const float* b2   = (const float*)d_in[21];
  const float* ln2g = (const float*)d_in[22];
  const float* ln2b = (const float*)d_in[23];
  float* out = (float*)d_out;
  char*  w   = (char*)d_ws;

  // workspace (74.05 MB total):
  unsigned short* Vb      = (unsigned short*)(w);                // 11,523,072
  unsigned short* attnpre = (unsigned short*)(w + 11523072);     // 11,523,072 (= x_bf)
  unsigned short* h1      = (unsigned short*)(w + 23046144);     // 46,092,288
  char*           tail    = w + 69138432;
  float*          attw    = (float*)(tail);                      //  2,880,768
  unsigned*       offp    = (unsigned*)(tail + 2880768);         //    720,192
  unsigned short* Wv_t    = (unsigned short*)(tail + 3600960);   //    131,072
  unsigned short* Wo_t    = (unsigned short*)(tail + 3732032);   //    131,072
  unsigned short* W1_t    = (unsigned short*)(tail + 3863104);   //    524,288
  unsigned short* W2_t    = (unsigned short*)(tail + 4387392);   //    524,288
  unsigned short* x_bf    = attnpre;
  unsigned short* src_bf  = h1;   // h1 region is free until gemm2 writes it

  pre_kernel<<<dim3(4160), 256, 0, stream>>>(
      src, src_bf, m0, m1, m2, m3, pm_w, pm_b, Wv, Wo, W1, W2,
      Wv_t, Wo_t, W1_t, W2_t, offp, attw);

  // V = bf16(src_bf @ Wv + bv)
  gemm_v6<0, 8><<<dim3(704, 1), 256, 0, stream>>>(
      (const short*)src_bf, (const short*)Wv_t, bv, nullptr, nullptr,
      nullptr, nullptr, nullptr, Vb, TOK, 256);

  // deformable attention -> attnpre (bf16)
  sample_kernel<<<dim3(5627), 256, 0, stream>>>(
      Vb, refpts, offp, attw, attnpre);

  // x_bf = bf16(LN1(attnpre @ Wo + bo + src))  (in-place block-local rewrite)
  gemm_v6<1, 8><<<dim3(704, 1), 256, 0, stream>>>(
      (const short*)attnpre, (const short*)Wo_t, bo, src, nullptr,
      ln1g, ln1b, nullptr, x_bf, TOK, 256);

  // h1 = bf16(relu(x_bf @ W1 + b1))   (overwrites src_bf — no longer needed)
  gemm_v6<2, 8><<<dim3(704, 4), 256, 0, stream>>>(
      (const short*)x_bf, (const short*)W1_t, b1, nullptr, nullptr,
      nullptr, nullptr, nullptr, h1, TOK, 1024);

  // out = LN2(h1 @ W2 + b2 + x_bf)
  gemm_v6<3, 10><<<dim3(704, 1), 256, 0, stream>>>(
      (const short*)h1, (const short*)W2_t, b2, nullptr, x_bf,
      ln2g, ln2b, out, nullptr, TOK, 256);
}

// Round 8
// 271.854 us; speedup vs baseline: 1.2303x; 1.2303x over previous
//
#include <hip/hip_runtime.h>
#include <cstddef>
#include <cstdint>

#define LEN_T 11253
#define TOK   22506     // BS * LEN
#define NHEADS 8
#define DMODEL 256

#define SBAR() __builtin_amdgcn_sched_barrier(0)

typedef __attribute__((ext_vector_type(8))) short short8;   // bf16x8 (4 VGPR)
typedef __attribute__((ext_vector_type(4))) float f32x4;

__device__ __forceinline__ unsigned short f2bf(float f) {
  union { float f; unsigned u; } v; v.f = f;
  unsigned r = v.u + 0x7fffu + ((v.u >> 16) & 1u);   // RNE
  return (unsigned short)(r >> 16);
}
__device__ __forceinline__ float bfhi2f(unsigned u) {
  union { unsigned u; float f; } v; v.u = u & 0xffff0000u; return v.f;
}
__device__ __forceinline__ float bflo2f(unsigned u) {
  union { unsigned u; float f; } v; v.u = u << 16; return v.f;
}
__device__ __forceinline__ float bf2f(unsigned short s) {
  union { unsigned u; float f; } v; v.u = (unsigned)s << 16; return v.f;
}
__device__ __forceinline__ void gld_lds16(const void* g, void* l) {
  __builtin_amdgcn_global_load_lds(
      (const __attribute__((address_space(1))) void*)g,
      (__attribute__((address_space(3))) void*)l, 16, 0, 0);
}

// branchless stable top-4 insert (desc, strict > : earlier index wins ties)
__device__ __forceinline__ void ins4(float v, int ji,
    float& t0, float& t1, float& t2, float& t3,
    int& i0, int& i1, int& i2, int& i3)
{
  bool a0 = v > t0, a1 = v > t1, a2 = v > t2, a3 = v > t3;
  t3 = a3 ? (a2 ? t2 : v) : t3;  i3 = a3 ? (a2 ? i2 : ji) : i3;
  t2 = a2 ? (a1 ? t1 : v) : t2;  i2 = a2 ? (a1 ? i1 : ji) : i2;
  t1 = a1 ? (a0 ? t0 : v) : t1;  i1 = a1 ? (a0 ? i0 : ji) : i1;
  t0 = a0 ? v : t0;              i0 = a0 ? ji : i0;
}

// ==== pre-kernel: top-k + weight casts into K-step-SLICED layout ====
// blocks [0,704): topk, one THREAD per (b,q,h)
// blocks [704,1024): weight cast: Bg[kb][n][32] slabs, one 16B per thread.
//   Stored slot s holds k-slot s ^ ((n+(n>>2))&3)  (bank swizzle baked in).
__global__ __launch_bounds__(256) void pre_kernel(
    const float* __restrict__ m0, const float* __restrict__ m1,
    const float* __restrict__ m2, const float* __restrict__ m3,
    const float* __restrict__ pm_w, const float* __restrict__ pm_b,
    const float* __restrict__ Wv, const float* __restrict__ Wo,
    const float* __restrict__ W1, const float* __restrict__ W2,
    unsigned short* __restrict__ Wv_g, unsigned short* __restrict__ Wo_g,
    unsigned short* __restrict__ W1_g, unsigned short* __restrict__ W2_g,
    unsigned* __restrict__ offp, float* __restrict__ attw)
{
  int blk = blockIdx.x;
  if (blk >= 704) {   // ---- weight cast into sliced layout
    int cb = blk - 704;
    const float* W; unsigned short* Bg; int lgN, base;
    if (cb < 32)       { W = Wv; Bg = Wv_g; lgN = 8;  base = cb; }
    else if (cb < 64)  { W = Wo; Bg = Wo_g; lgN = 8;  base = cb - 32; }
    else if (cb < 192) { W = W1; Bg = W1_g; lgN = 10; base = cb - 64; }
    else               { W = W2; Bg = W2_g; lgN = 8;  base = cb - 192; }
    int idx = base * 256 + threadIdx.x;     // one 16B chunk (8 shorts)
    int s   = idx & 3;
    int n   = (idx >> 2) & ((1 << lgN) - 1);
    int kb  = idx >> (2 + lgN);
    int k0  = kb * 32 + ((s ^ ((n + (n >> 2)) & 3)) << 3);
    const float* wp = W + (size_t)k0 * (1 << lgN) + n;
    unsigned short e[8];
    #pragma unroll
    for (int j = 0; j < 8; ++j) e[j] = f2bf(wp[(size_t)j << lgN]);
    uint4 o;
    o.x = (unsigned)e[0] | ((unsigned)e[1] << 16);
    o.y = (unsigned)e[2] | ((unsigned)e[3] << 16);
    o.z = (unsigned)e[4] | ((unsigned)e[5] << 16);
    o.w = (unsigned)e[6] | ((unsigned)e[7] << 16);
    *(uint4*)(Bg + (size_t)idx * 8) = o;
    return;
  }
  // ---- top-k: one thread per (b, q, h) ----
  int t = blk * 256 + threadIdx.x;
  if (t >= TOK * NHEADS) return;
  int h  = t & 7;
  int bq = t >> 3;
  int b  = bq / LEN_T;
  int q  = bq - b * LEN_T;
  int l, H_, W_;
  const float* mk;
  if (q < 8464)       { l = 0; H_ = 92; W_ = 92; mk = m0; }
  else if (q < 10580) { l = 1; H_ = 46; W_ = 46; mk = m1; }
  else if (q < 11109) { l = 2; H_ = 23; W_ = 23; mk = m2; }
  else                { l = 3; H_ = 12; W_ = 12; mk = m3; }
  int st = (l == 0) ? 0 : (l == 1) ? 8464 : (l == 2) ? 10580 : 11109;
  int pos = q - st;
  int rr = pos / W_;
  int cc = pos - rr * W_;
  float w  = pm_w[l * NHEADS + h];
  float bb = pm_b[l * NHEADS + h];
  const float* mp = mk + (size_t)b * H_ * W_;

  float t0=-1e30f,t1=-1e30f,t2=-1e30f,t3=-1e30f;
  int   i0=0,i1=0,i2=0,i3=0;
  for (int i = 0; i < 7; ++i) {
    int yy = rr + i - 3;
    #pragma unroll
    for (int j = 0; j < 7; ++j) {
      int xx = cc + j - 3;
      float v = 0.f;                       // zero padding outside the map
      if (yy >= 0 && yy < H_ && xx >= 0 && xx < W_)
        v = mp[(size_t)yy * W_ + xx] * w + bb;
      ins4(v, j | (i << 4), t0, t1, t2, t3, i0, i1, i2, i3);
    }
  }
  float e1 = __expf(t1 - t0);
  float e2 = __expf(t2 - t0);
  float e3 = __expf(t3 - t0);
  float inv = 1.f / (4.f * (1.f + e1 + e2 + e3));
  float4 wout; wout.x = inv; wout.y = e1 * inv; wout.z = e2 * inv; wout.w = e3 * inv;
  *(float4*)(attw + (size_t)t * 4) = wout;
  offp[t] = (unsigned)i0 | ((unsigned)i1 << 8)
          | ((unsigned)i2 << 16) | ((unsigned)i3 << 24);
}

// ---------------- deformable bilinear sampling (bf16 V, v3) ----------------
// one wave per token; XCD-contiguous token swizzle for L2 locality.
// grid MUST be 5627 blocks (= 8*703 + 3).
__global__ __launch_bounds__(256) void sample_kernel(
    const unsigned short* __restrict__ Vb, const float* __restrict__ refpts,
    const unsigned* __restrict__ offp, const float* __restrict__ attw,
    unsigned short* __restrict__ outp)
{
  __shared__ int4  sidx[4][128];
  __shared__ float4 swgt[4][128];
  const int wv   = threadIdx.x >> 6;
  const int lane = threadIdx.x & 63;
  const int bx = blockIdx.x & 7, by = blockIdx.x >> 3;
  const int nb = bx * 703 + min(bx, 3) + by;
  const int blk = nb * 4 + wv;             // b*LEN + q
  const bool ok = blk < TOK;

  if (ok) {
    const int b = (blk >= LEN_T) ? 1 : 0;
    const float* rp = refpts + (size_t)blk * 8;
    #pragma unroll
    for (int e = 0; e < 2; ++e) {
      int t = lane * 2 + e;                // t = lp*8 + h
      int h = t & 7, lp = t >> 3;
      int l = lp >> 2, p = lp & 3;
      unsigned pb = (offp[(size_t)blk * 8 + h] >> (8 * p)) & 0xffu;
      float ox = (float)(int)(pb & 15u) - 3.f;
      float oy = (float)(int)(pb >> 4)  - 3.f;
      float aw = attw[((size_t)blk * 8 + h) * 4 + p];
      int H_ = (l == 0) ? 92 : (l == 1) ? 46 : (l == 2) ? 23 : 12;
      int st = (l == 0) ? 0  : (l == 1) ? 8464 : (l == 2) ? 10580 : 11109;
      float xx = rp[2 * l]     * (float)H_ - 0.5f + ox;
      float yy = rp[2 * l + 1] * (float)H_ - 0.5f + oy;
      float x0f = floorf(xx), y0f = floorf(yy);
      float tx = xx - x0f, ty = yy - y0f;
      int x0 = (int)x0f, y0 = (int)y0f;
      int base = b * LEN_T + st;
      float wc[4] = {(1.f - tx) * (1.f - ty), tx * (1.f - ty),
                     (1.f - tx) * ty,         tx * ty};
      int4 idx; float4 wg;
      int xs[4] = {x0, x0 + 1, x0, x0 + 1};
      int ys[4] = {y0, y0, y0 + 1, y0 + 1};
      int   id[4]; float wgt[4];
      #pragma unroll
      for (int c = 0; c < 4; ++c) {
        int xi = xs[c], yi = ys[c];
        bool v_ = (xi >= 0) & (xi < H_) & (yi >= 0) & (yi < H_);
        id[c]  = base + min(max(yi, 0), H_ - 1) * H_ + min(max(xi, 0), H_ - 1);
        wgt[c] = v_ ? aw * wc[c] : 0.f;
      }
      idx.x = id[0]; idx.y = id[1]; idx.z = id[2]; idx.w = id[3];
      wg.x = wgt[0]; wg.y = wgt[1]; wg.z = wgt[2]; wg.w = wgt[3];
      sidx[wv][t] = idx;
      swgt[wv][t] = wg;
    }
  }
  __syncthreads();

  if (ok) {
    const int h = lane >> 3, dg = lane & 7;
    const unsigned short* vb = Vb + h * 32 + dg * 4;   // 4 bf16 = 8B per lane
    f32x4 acc = {0.f, 0.f, 0.f, 0.f};

    // double-buffered pipeline state; ALL indices compile-time after unroll
    uint2  u[2][8];
    float4 wg[2][2];

    // issue batch 0 (lp = 0,1)
    #pragma unroll
    for (int j = 0; j < 2; ++j) {
      int4 idx  = sidx[wv][j * 8 + h];
      wg[0][j]  = swgt[wv][j * 8 + h];
      u[0][j*4+0] = *(const uint2*)(vb + (size_t)idx.x * DMODEL);
      u[0][j*4+1] = *(const uint2*)(vb + (size_t)idx.y * DMODEL);
      u[0][j*4+2] = *(const uint2*)(vb + (size_t)idx.z * DMODEL);
      u[0][j*4+3] = *(const uint2*)(vb + (size_t)idx.w * DMODEL);
    }
    SBAR();
    #pragma unroll
    for (int bt = 0; bt < 8; ++bt) {
      const int cur = bt & 1, nxt = cur ^ 1;
      if (bt < 7) {      // issue batch bt+1 while batch bt's data arrives
        #pragma unroll
        for (int j = 0; j < 2; ++j) {
          int lp = (bt + 1) * 2 + j;
          int4 idx   = sidx[wv][lp * 8 + h];
          wg[nxt][j] = swgt[wv][lp * 8 + h];
          u[nxt][j*4+0] = *(const uint2*)(vb + (size_t)idx.x * DMODEL);
          u[nxt][j*4+1] = *(const uint2*)(vb + (size_t)idx.y * DMODEL);
          u[nxt][j*4+2] = *(const uint2*)(vb + (size_t)idx.z * DMODEL);
          u[nxt][j*4+3] = *(const uint2*)(vb + (size_t)idx.w * DMODEL);
        }
      }
      SBAR();            // pin: prefetch issued above, consume below
      #pragma unroll
      for (int j = 0; j < 2; ++j) {
        const float4 w4 = wg[cur][j];
        const uint2 u0 = u[cur][j*4+0], u1 = u[cur][j*4+1];
        const uint2 u2 = u[cur][j*4+2], u3 = u[cur][j*4+3];
        acc.x += w4.x * bflo2f(u0.x) + w4.y * bflo2f(u1.x) + w4.z * bflo2f(u2.x) + w4.w * bflo2f(u3.x);
        acc.y += w4.x * bfhi2f(u0.x) + w4.y * bfhi2f(u1.x) + w4.z * bfhi2f(u2.x) + w4.w * bfhi2f(u3.x);
        acc.z += w4.x * bflo2f(u0.y) + w4.y * bflo2f(u1.y) + w4.z * bflo2f(u2.y) + w4.w * bflo2f(u3.y);
        acc.w += w4.x * bfhi2f(u0.y) + w4.y * bfhi2f(u1.y) + w4.z * bfhi2f(u2.y) + w4.w * bfhi2f(u3.y);
      }
    }
    uint2 o;
    o.x = (unsigned)f2bf(acc.x) | ((unsigned)f2bf(acc.y) << 16);
    o.y = (unsigned)f2bf(acc.z) | ((unsigned)f2bf(acc.w) << 16);
    *(uint2*)(outp + (size_t)blk * DMODEL + h * 32 + dg * 4) = o;
  }
}

// ===== v7: LDS-tiled GEMM with SLICED-B (coalesced staging), 32x256 =====
// C[M,N] = A[M,K] @ W[K,N] via sliced Bg[kb][n][32]. Block = 32(M) x 256(N),
// 4 waves, each wave 32x64 outputs (acc[2][4]). A: 2x2KB dbuf (tid<128 stage,
// v4's measured-zero-conflict swizzle). B: 2x16KB dbuf; staging is 4x fully
// contiguous 1KB-per-wave gld_lds from the sliced layout (16x fewer line
// requests than per-lane n*K gathers — rounds 0-6's ~1TB/s binder); read
// swizzle s = quad ^ ((n+(n>>2))&3) baked into the layout -> 2-way (free).
// One __syncthreads per K-step (v4 loop, measured best). LDS 37KB, lb(256,3)
// -> 3 blocks/CU resident; grid 704 = 2.75/CU for barrier-drain overlap.
// EPI 0: Cb=bf16(acc+bias)  EPI 1: LN(+res_f32)->Cb  EPI 2: relu->Cb
// EPI 3: LN(+resb_bf16)->C f32.  AF32: A is f32, inline cast during staging.
template<int EPI, bool AF32, int KC>
__global__ __launch_bounds__(256, 3) void gemm_v7(
    const void* __restrict__ Aptr, const unsigned short* __restrict__ Bg,
    const float* __restrict__ bias, const float* __restrict__ res,
    const unsigned short* __restrict__ resb,
    const float* __restrict__ lng, const float* __restrict__ lnb,
    float* __restrict__ C, unsigned short* __restrict__ Cb,
    int M, int N)
{
  constexpr int K  = KC * 256;
  constexpr int NK = KC * 8;
  __shared__ short As[2][32 * 32]  __attribute__((aligned(16)));   // 2 x 2 KB
  __shared__ short Bs[2][256 * 32] __attribute__((aligned(16)));   // 2 x 16 KB
  __shared__ float2 lnred[32][4];
  const int tid = threadIdx.x, w = tid >> 6, lane = tid & 63;
  const int row0  = blockIdx.x * 32;
  const int ncol0 = blockIdx.y * 256;
  const int wn0   = ncol0 + w * 64;
  const int colq = lane & 15, quad = lane >> 4;

  f32x4 acc[2][4];
  #pragma unroll
  for (int i = 0; i < 2; ++i)
    #pragma unroll
    for (int j = 0; j < 4; ++j) acc[i][j] = (f32x4){0.f, 0.f, 0.f, 0.f};

  // A staging (tid < 128): row = tid>>2, stored slot = tid&3,
  // source k-slot = (tid&3) ^ ((tid>>3)&3)  [content(r,s) = s^((r>>1)&3)]
  const int rA   = min(row0 + (tid >> 2), M - 1);
  const int ksw8 = (((tid & 3) ^ ((tid >> 3) & 3)) << 3);
  const float* Af = (const float*)Aptr;
  const short* Ab = (const short*)Aptr;

  auto stageA = [&](int kb, int nbuf) {
    if (tid < 128) {
      if constexpr (AF32) {
        const float* ap = Af + (size_t)rA * K + kb * 32 + ksw8;
        float4 f0 = *(const float4*)ap;
        float4 f1 = *(const float4*)(ap + 4);
        uint4 u;
        u.x = (unsigned)f2bf(f0.x) | ((unsigned)f2bf(f0.y) << 16);
        u.y = (unsigned)f2bf(f0.z) | ((unsigned)f2bf(f0.w) << 16);
        u.z = (unsigned)f2bf(f1.x) | ((unsigned)f2bf(f1.y) << 16);
        u.w = (unsigned)f2bf(f1.z) | ((unsigned)f2bf(f1.w) << 16);
        *(uint4*)(As[nbuf] + (size_t)tid * 8) = u;
      } else {
        gld_lds16(Ab + (size_t)rA * K + kb * 32 + ksw8,
                  As[nbuf] + (size_t)tid * 8);
      }
    }
  };
  // B staging: 4 x contiguous 4KB rounds (1KB per wave-instruction)
  auto stageB = [&](int kb, int nbuf) {
    const unsigned short* slab = Bg + ((size_t)kb * N + ncol0) * 32;
    #pragma unroll
    for (int j = 0; j < 4; ++j)
      gld_lds16(slab + j * 2048 + tid * 8, Bs[nbuf] + j * 2048 + (size_t)tid * 8);
  };

  const int rdoA = ((quad ^ ((colq >> 1) & 3)) << 3);

  stageA(0, 0); stageB(0, 0);
  __syncthreads();
  int buf = 0;
  for (int kb = 0; kb < NK; ++kb) {
    if (kb + 1 < NK) { stageA(kb + 1, buf ^ 1); stageB(kb + 1, buf ^ 1); }
    short8 af[2], bf[4];
    #pragma unroll
    for (int mt = 0; mt < 2; ++mt)
      af[mt] = *(const short8*)(As[buf] + (mt * 16 + colq) * 32 + rdoA);
    #pragma unroll
    for (int nt = 0; nt < 4; ++nt) {
      int nl = w * 64 + nt * 16 + colq;
      bf[nt] = *(const short8*)(Bs[buf] + nl * 32
                                + ((quad ^ ((nl + (nl >> 2)) & 3)) << 3));
    }
    #pragma unroll
    for (int mt = 0; mt < 2; ++mt)
      #pragma unroll
      for (int nt = 0; nt < 4; ++nt)
        acc[mt][nt] = __builtin_amdgcn_mfma_f32_16x16x32_bf16(
            af[mt], bf[nt], acc[mt][nt], 0, 0, 0);
    __syncthreads();
    buf ^= 1;
  }

  // ---- epilogue: C/D layout col = lane&15, row = quad*4 + reg ----
  float bia[4];
  #pragma unroll
  for (int nt = 0; nt < 4; ++nt) bia[nt] = bias[wn0 + nt * 16 + colq];

  if constexpr (EPI == 1 || EPI == 3) {
    #pragma unroll
    for (int mt = 0; mt < 2; ++mt) {
      #pragma unroll
      for (int r = 0; r < 4; ++r) {
        int lrow = mt * 16 + quad * 4 + r;
        int rowc = min(row0 + lrow, M - 1);
        float s = 0.f, sq = 0.f;
        #pragma unroll
        for (int nt = 0; nt < 4; ++nt) {
          float rv;
          if constexpr (EPI == 1)
            rv = res[(size_t)rowc * 256 + wn0 + nt * 16 + colq];
          else
            rv = bf2f(resb[(size_t)rowc * 256 + wn0 + nt * 16 + colq]);
          float f = acc[mt][nt][r] + bia[nt] + rv;
          acc[mt][nt][r] = f;
          s += f; sq += f * f;
        }
        #pragma unroll
        for (int off = 1; off < 16; off <<= 1) {
          s  += __shfl_xor(s,  off, 64);
          sq += __shfl_xor(sq, off, 64);
        }
        if (colq == 0) lnred[lrow][w] = (float2){s, sq};
      }
    }
    __syncthreads();
    #pragma unroll
    for (int mt = 0; mt < 2; ++mt) {
      #pragma unroll
      for (int r = 0; r < 4; ++r) {
        int lrow = mt * 16 + quad * 4 + r;
        int row  = row0 + lrow;
        if (row >= M) continue;
        float2 p0 = lnred[lrow][0], p1 = lnred[lrow][1];
        float2 p2 = lnred[lrow][2], p3 = lnred[lrow][3];
        float mu  = (p0.x + p1.x + p2.x + p3.x) * (1.f / 256.f);
        float var = (p0.y + p1.y + p2.y + p3.y) * (1.f / 256.f) - mu * mu;
        float rs  = rsqrtf(var + 1e-5f);          // biased var (jnp.var)
        #pragma unroll
        for (int nt = 0; nt < 4; ++nt) {
          int col = wn0 + nt * 16 + colq;
          float o = (acc[mt][nt][r] - mu) * rs * lng[col] + lnb[col];
          if constexpr (EPI == 1)
            Cb[(size_t)row * 256 + col] = f2bf(o);
          else
            C[(size_t)row * 256 + col] = o;
        }
      }
    }
  } else {
    #pragma unroll
    for (int mt = 0; mt < 2; ++mt) {
      #pragma unroll
      for (int r = 0; r < 4; ++r) {
        int row = row0 + mt * 16 + quad * 4 + r;
        if (row < M) {
          #pragma unroll
          for (int nt = 0; nt < 4; ++nt) {
            float f = acc[mt][nt][r] + bia[nt];
            if constexpr (EPI == 2) f = fmaxf(f, 0.f);
            Cb[(size_t)row * N + wn0 + nt * 16 + colq] = f2bf(f);
          }
        }
      }
    }
  }
}

extern "C" void kernel_launch(void* const* d_in, const int* in_sizes, int n_in,
                              void* d_out, int out_size, void* d_ws, size_t ws_size,
                              hipStream_t stream)
{
  const float* src    = (const float*)d_in[0];
  const float* refpts = (const float*)d_in[2];
  const float* m0   = (const float*)d_in[4];
  const float* m1   = (const float*)d_in[5];
  const float* m2   = (const float*)d_in[6];
  const float* m3   = (const float*)d_in[7];
  const float* pm_w = (const float*)d_in[10];
  const float* pm_b = (const float*)d_in[11];
  const float* Wv   = (const float*)d_in[12];
  const float* bv   = (const float*)d_in[13];
  const float* Wo   = (const float*)d_in[14];
  const float* bo   = (const float*)d_in[15];
  const float* ln1g = (const float*)d_in[16];
  const float* ln1b = (const float*)d_in[17];
  const float* W1   = (const float*)d_in[18];
  const float* b1   = (const float*)d_in[19];
  const float* W2   = (const float*)d_in[20];
  const float* b2   = (const float*)d_in[21];
  const float* ln2g = (const float*)d_in[22];
  const float* ln2b = (const float*)d_in[23];
  float* out = (float*)d_out;
  char*  w   = (char*)d_ws;

  // workspace (74.05 MB total):
  unsigned short* Vb      = (unsigned short*)(w);                // 11,523,072
  unsigned short* attnpre = (unsigned short*)(w + 11523072);     // 11,523,072 (= x_bf)
  unsigned short* h1      = (unsigned short*)(w + 23046144);     // 46,092,288
  char*           tail    = w + 69138432;
  float*          attw    = (float*)(tail);                      //  2,880,768
  unsigned*       offp    = (unsigned*)(tail + 2880768);         //    720,192
  unsigned short* Wv_g    = (unsigned short*)(tail + 3600960);   //    131,072
  unsigned short* Wo_g    = (unsigned short*)(tail + 3732032);   //    131,072
  unsigned short* W1_g    = (unsigned short*)(tail + 3863104);   //    524,288
  unsigned short* W2_g    = (unsigned short*)(tail + 4387392);   //    524,288
  unsigned short* x_bf    = attnpre;

  pre_kernel<<<dim3(1024), 256, 0, stream>>>(
      m0, m1, m2, m3, pm_w, pm_b, Wv, Wo, W1, W2,
      Wv_g, Wo_g, W1_g, W2_g, offp, attw);

  // V = bf16(src @ Wv + bv), inline f32->bf16 A cast
  gemm_v7<0, true, 1><<<dim3(704, 1), 256, 0, stream>>>(
      src, Wv_g, bv, nullptr, nullptr, nullptr, nullptr,
      nullptr, Vb, TOK, 256);

  // deformable attention -> attnpre (bf16)
  sample_kernel<<<dim3(5627), 256, 0, stream>>>(
      Vb, refpts, offp, attw, attnpre);

  // x_bf = bf16(LN1(attnpre @ Wo + bo + src))  (in-place block-local rewrite)
  gemm_v7<1, false, 1><<<dim3(704, 1), 256, 0, stream>>>(
      attnpre, Wo_g, bo, src, nullptr, ln1g, ln1b,
      nullptr, x_bf, TOK, 256);

  // h1 = bf16(relu(x_bf @ W1 + b1))
  gemm_v7<2, false, 1><<<dim3(704, 4), 256, 0, stream>>>(
      x_bf, W1_g, b1, nullptr, nullptr, nullptr, nullptr,
      nullptr, h1, TOK, 1024);

  // out = LN2(h1 @ W2 + b2 + x_bf)
  gemm_v7<3, false, 4><<<dim3(704, 1), 256, 0, stream>>>(
      h1, W2_g, b2, nullptr, x_bf, ln2g, ln2b,
      out, nullptr, TOK, 256);
}